// Round 1
// 206.223 us; speedup vs baseline: 1.0042x; 1.0042x over previous
//
#include <hip/hip_runtime.h>
#include <math.h>

// Problem constants (CosineWeights): B=32, H=8, J=8192, K=128, fp32.
constexpr int B_ = 32;
constexpr int H_ = 8;
constexpr int J_ = 8192;
constexpr int K_ = 128;
constexpr float EPS_ = 1e-6f;

constexpr int SBLK = 64;          // j-blocks per batch i
constexpr int JPB  = J_ / SBLK;   // 128 rows per block
constexpr int RPI  = 8;           // rows per block-iteration (2 wave-pairs x 4 groups)
constexpr int ITERS = JPB / RPI;  // 16

// ---------------- DPP helpers (all-VALU, no LDS pipe) ----------------
// ctrl codes: quad_perm[1,0,3,2]=0xB1 (lane^1), quad_perm[2,3,0,1]=0x4E (lane^2),
// row_ror:4=0x124, row_ror:8=0x128 (rotations within the 16-lane row).
#define QPX1 0xB1
#define QPX2 0x4E
#define ROR4 0x124
#define ROR8 0x128

template <int CTRL>
__device__ __forceinline__ float dpp_mov(float x) {
  return __int_as_float(
      __builtin_amdgcn_update_dpp(0, __float_as_int(x), CTRL, 0xF, 0xF, true));
}
template <int CTRL>
__device__ __forceinline__ float dpp_add(float a, float b) {  // a + dpp(b)
  return a + dpp_mov<CTRL>(b);
}

__device__ __forceinline__ float dot4f(const float4 a, const float4 b, float acc) {
  acc = fmaf(a.x, b.x, acc);
  acc = fmaf(a.y, b.y, acc);
  acc = fmaf(a.z, b.z, acc);
  acc = fmaf(a.w, b.w, acc);
  return acc;
}

// ---------------- Kernel 1: fused coeffs + projection + norm + sharpen --------
// Head-split layout: waves 0-1 compute heads 0-3, waves 2-3 heads 4-7 (sibling
// waves stream the same memory rows; duplicates hit L1/L2, HBM fetch unchanged).
// Within a wave: 4 groups of 16 lanes; each group owns one row per iteration;
// lane sub owns float4 k-chunks {sub, sub+16}.
//
// BAKED-PERMUTATION FOLD REDUCTION (this revision's change):
// Lane s loads head (t ^ (s&3)) into coefficient slot t. Then the 8-value
// (4 heads x {proj,norm}) x 16-lane reduction needs no cndmask selects:
//   stage A: fold slot-bit1 with quad_perm xor2   (4 outputs, head stays t0^(s&3))
//   stage B: fold slot-bit0 with quad_perm xor1   (2 outputs, head = s&3)
//   tail   : += row_ror:4, += row_ror:8           (rotation preserves lane&3)
// Final: every lane holds the 16-lane totals for head (lane&3).
// 20 VALU instrs vs 64 for the old per-value red16, and zero select chains.
__global__ __launch_bounds__(256, 4) void cw_main(
    const float* __restrict__ memory, const float* __restrict__ keys,
    const float* __restrict__ strengths, const float* __restrict__ mask,
    float* __restrict__ out)
{
  const int bid  = blockIdx.x;
  const int i    = bid >> 6;     // / SBLK
  const int jb   = bid & 63;     // % SBLK
  const int t    = threadIdx.x;
  const int wave = t >> 6;
  const int lane = t & 63;
  const int grp  = lane >> 4;    // 0..3 (row within wave)
  const int sub  = lane & 15;    // 0..15 (k position)
  const int hs   = (wave >> 1) << 2;  // head-set base: 0 or 4
  const int q    = sub & 3;           // this lane's final head (hs + q)

  // ---- Per-block coefficient build (amortized over 128 rows) ----
  const float4* keyv = (const float4*)(keys + (size_t)i * H_ * K_);
  const float4* mskv = (const float4*)(mask + (size_t)i * H_ * K_);
  float4 cA[4][2];   // slot t: mask^2 * keys of head hs + (t^q)
  float4 cB[4][2];   // slot t: mask^2        of head hs + (t^q)
  float knp[4];      // slot t: partial ||mask*keys||^2 of head hs + (t^q)
  #pragma unroll
  for (int tt = 0; tt < 4; ++tt) {
    const int h = hs + (tt ^ q);   // baked fold permutation
    float kp = 0.0f;
    #pragma unroll
    for (int c = 0; c < 2; ++c) {
      const float4 kv = keyv[h * 32 + c * 16 + sub];
      const float4 mv = mskv[h * 32 + c * 16 + sub];
      float4 b, a;
      b.x = mv.x * mv.x; b.y = mv.y * mv.y; b.z = mv.z * mv.z; b.w = mv.w * mv.w;
      a.x = b.x * kv.x;  a.y = b.y * kv.y;  a.z = b.z * kv.z;  a.w = b.w * kv.w;
      cB[tt][c] = b;
      cA[tt][c] = a;
      kp = dot4f(a, kv, kp);   // m^2 * k^2
    }
    knp[tt] = kp;
  }
  // Fold-reduce kn: lane ends with ||mask*keys||^2 of head hs+q.
  {
    const float wk0 = dpp_add<QPX2>(knp[0], knp[2]);
    const float wk1 = dpp_add<QPX2>(knp[1], knp[3]);
    float xk = dpp_add<QPX1>(wk0, wk1);
    xk = dpp_add<ROR4>(xk, xk);
    xk = dpp_add<ROR8>(xk, xk);
    knp[0] = xk;
  }
  const float knorm = sqrtf(knp[0]);
  const float st = strengths[i * H_ + hs + q];
  const float sp = fmaxf(st, 0.0f) + log1pf(expf(-fabsf(st)));  // softplus

  // ---- Stream memory rows ----
  const int jrow0 = (wave & 1) * 4 + grp;          // row offset within iteration
  const int j0    = jb * JPB + jrow0;
  const float4* rowv = (const float4*)(memory + ((size_t)i * J_ + j0) * K_);
  // RPI rows per iteration -> advance RPI*K_/4 = 256 float4 per it.

  float4 m0 = rowv[sub];
  float4 m1 = rowv[sub + 16];

  #pragma unroll 1
  for (int it = 0; it < ITERS; ++it) {
    // Branchless, always-in-bounds prefetch (last iter re-reads row 0).
    const int nx = (it + 1) & (ITERS - 1);
    const float4* nr = rowv + (size_t)nx * 256;
    const float4 n0v = nr[sub];
    const float4 n1v = nr[sub + 16];

    float4 sq0, sq1;
    sq0.x = m0.x * m0.x; sq0.y = m0.y * m0.y; sq0.z = m0.z * m0.z; sq0.w = m0.w * m0.w;
    sq1.x = m1.x * m1.x; sq1.y = m1.y * m1.y; sq1.z = m1.z * m1.z; sq1.w = m1.w * m1.w;

    float p[4], nn[4];
    #pragma unroll
    for (int hh = 0; hh < 4; ++hh) {
      float a = m0.x * cA[hh][0].x;
      a = fmaf(m0.y, cA[hh][0].y, a);
      a = fmaf(m0.z, cA[hh][0].z, a);
      a = fmaf(m0.w, cA[hh][0].w, a);
      a = dot4f(m1, cA[hh][1], a);
      p[hh] = a;
      float b = sq0.x * cB[hh][0].x;
      b = fmaf(sq0.y, cB[hh][0].y, b);
      b = fmaf(sq0.z, cB[hh][0].z, b);
      b = fmaf(sq0.w, cB[hh][0].w, b);
      b = dot4f(sq1, cB[hh][1], b);
      nn[hh] = b;
    }

    // Select-free fold reduction (20 VALU instrs for all 8 values).
    const float w0 = dpp_add<QPX2>(p[0],  p[2]);
    const float w1 = dpp_add<QPX2>(p[1],  p[3]);
    const float u0 = dpp_add<QPX2>(nn[0], nn[2]);
    const float u1 = dpp_add<QPX2>(nn[1], nn[3]);
    float xp = dpp_add<QPX1>(w0, w1);
    float xn = dpp_add<QPX1>(u0, u1);
    xp = dpp_add<ROR4>(xp, xp);
    xn = dpp_add<ROR4>(xn, xn);
    xp = dpp_add<ROR8>(xp, xp);
    xn = dpp_add<ROR8>(xn, xn);
    // Now lane s holds: xp = projections[head hs+(s&3)], xn = ||m*mem||^2.

    if (sub < 4) {
      const float mnorm = sqrtf(xn);
      const float sharp = xp / fmaf(knorm, mnorm, EPS_) * sp;
      const int j = jb * JPB + it * RPI + jrow0;
      out[((size_t)(i * H_ + hs + sub)) * J_ + j] = sharp;
    }

    m0 = n0v;
    m1 = n1v;
  }
}

// ---------------- Kernel 2: in-place softmax over J per (i,h) row ----------------
// 1024 threads/block (16 waves); each thread owns 2 float4.
__global__ __launch_bounds__(1024) void cw_softmax(float* __restrict__ out)
{
  const int row = blockIdx.x;   // 0..255
  float4* pv = (float4*)(out + (size_t)row * J_);
  const int t = threadIdx.x;
  const int wave = t >> 6, lane = t & 63;

  float4 v0 = pv[t];
  float4 v1 = pv[t + 1024];
  float mx = fmaxf(fmaxf(fmaxf(v0.x, v0.y), fmaxf(v0.z, v0.w)),
                   fmaxf(fmaxf(v1.x, v1.y), fmaxf(v1.z, v1.w)));
  #pragma unroll
  for (int o = 32; o > 0; o >>= 1) mx = fmaxf(mx, __shfl_xor(mx, o, 64));
  __shared__ float sm[16];
  __shared__ float ss[16];
  if (lane == 0) sm[wave] = mx;
  __syncthreads();
  mx = sm[lane & 15];
  #pragma unroll
  for (int o = 8; o > 0; o >>= 1) mx = fmaxf(mx, __shfl_xor(mx, o, 64));

  v0.x = __expf(v0.x - mx); v0.y = __expf(v0.y - mx);
  v0.z = __expf(v0.z - mx); v0.w = __expf(v0.w - mx);
  v1.x = __expf(v1.x - mx); v1.y = __expf(v1.y - mx);
  v1.z = __expf(v1.z - mx); v1.w = __expf(v1.w - mx);
  float sum = ((v0.x + v0.y) + (v0.z + v0.w)) + ((v1.x + v1.y) + (v1.z + v1.w));
  #pragma unroll
  for (int o = 32; o > 0; o >>= 1) sum += __shfl_xor(sum, o, 64);
  if (lane == 0) ss[wave] = sum;
  __syncthreads();
  sum = ss[lane & 15];
  #pragma unroll
  for (int o = 8; o > 0; o >>= 1) sum += __shfl_xor(sum, o, 64);
  const float inv = 1.0f / sum;

  v0.x *= inv; v0.y *= inv; v0.z *= inv; v0.w *= inv;
  v1.x *= inv; v1.y *= inv; v1.z *= inv; v1.w *= inv;
  pv[t] = v0;
  pv[t + 1024] = v1;
}

extern "C" void kernel_launch(void* const* d_in, const int* in_sizes, int n_in,
                              void* d_out, int out_size, void* d_ws, size_t ws_size,
                              hipStream_t stream) {
  const float* memory    = (const float*)d_in[0];  // [B,J,K]
  const float* keys      = (const float*)d_in[1];  // [B,H,K]
  const float* strengths = (const float*)d_in[2];  // [B,H,1]
  const float* mask      = (const float*)d_in[3];  // [B,H,K]
  float* out = (float*)d_out;                      // [B,H,J]

  // NOTE: d_ws intentionally unused — all coefficients computed in-kernel.
  (void)d_ws; (void)ws_size;

  cw_main<<<B_ * SBLK, 256, 0, stream>>>(memory, keys, strengths, mask, out);
  cw_softmax<<<B_ * H_, 1024, 0, stream>>>(out);
}

// Round 2
// 205.631 us; speedup vs baseline: 1.0071x; 1.0029x over previous
//
#include <hip/hip_runtime.h>
#include <math.h>

// Problem constants (CosineWeights): B=32, H=8, J=8192, K=128, fp32.
constexpr int B_ = 32;
constexpr int H_ = 8;
constexpr int J_ = 8192;
constexpr int K_ = 128;
constexpr float EPS_ = 1e-6f;

constexpr int SBLK = 64;          // j-blocks per batch i
constexpr int JPB  = J_ / SBLK;   // 128 rows per block
constexpr int RPI  = 8;           // rows per block-iteration (2 wave-pairs x 4 groups)
constexpr int ITERS = JPB / RPI;  // 16

// ---------------- DPP helpers (all-VALU, no LDS pipe) ----------------
// ctrl codes: quad_perm[1,0,3,2]=0xB1 (lane^1), quad_perm[2,3,0,1]=0x4E (lane^2),
// row_ror:4=0x124, row_ror:8=0x128 (rotations within the 16-lane row).
#define QPX1 0xB1
#define QPX2 0x4E
#define ROR4 0x124
#define ROR8 0x128

template <int CTRL>
__device__ __forceinline__ float dpp_mov(float x) {
  return __int_as_float(
      __builtin_amdgcn_update_dpp(0, __float_as_int(x), CTRL, 0xF, 0xF, true));
}
template <int CTRL>
__device__ __forceinline__ float dpp_add(float a, float b) {  // a + dpp(b)
  return a + dpp_mov<CTRL>(b);
}

__device__ __forceinline__ float dot4f(const float4 a, const float4 b, float acc) {
  acc = fmaf(a.x, b.x, acc);
  acc = fmaf(a.y, b.y, acc);
  acc = fmaf(a.z, b.z, acc);
  acc = fmaf(a.w, b.w, acc);
  return acc;
}

// Per-row body: dot products vs 4 heads, select-free fold reduction, epilogue.
// (See kernel comment for the baked-permutation layout.)
__device__ __forceinline__ void cw_row_compute(
    const float4 m0, const float4 m1,
    const float4 (&cA)[4][2], const float4 (&cB)[4][2],
    const float knorm, const float sp, const int sub, const int j,
    float* __restrict__ ouths /* out + (i*H+hs)*J */)
{
  float4 sq0, sq1;
  sq0.x = m0.x * m0.x; sq0.y = m0.y * m0.y; sq0.z = m0.z * m0.z; sq0.w = m0.w * m0.w;
  sq1.x = m1.x * m1.x; sq1.y = m1.y * m1.y; sq1.z = m1.z * m1.z; sq1.w = m1.w * m1.w;

  float p[4], nn[4];
  #pragma unroll
  for (int hh = 0; hh < 4; ++hh) {
    float a = m0.x * cA[hh][0].x;
    a = fmaf(m0.y, cA[hh][0].y, a);
    a = fmaf(m0.z, cA[hh][0].z, a);
    a = fmaf(m0.w, cA[hh][0].w, a);
    a = dot4f(m1, cA[hh][1], a);
    p[hh] = a;
    float b = sq0.x * cB[hh][0].x;
    b = fmaf(sq0.y, cB[hh][0].y, b);
    b = fmaf(sq0.z, cB[hh][0].z, b);
    b = fmaf(sq0.w, cB[hh][0].w, b);
    b = dot4f(sq1, cB[hh][1], b);
    nn[hh] = b;
  }

  // Select-free fold reduction (20 VALU instrs for all 8 values).
  const float w0 = dpp_add<QPX2>(p[0],  p[2]);
  const float w1 = dpp_add<QPX2>(p[1],  p[3]);
  const float u0 = dpp_add<QPX2>(nn[0], nn[2]);
  const float u1 = dpp_add<QPX2>(nn[1], nn[3]);
  float xp = dpp_add<QPX1>(w0, w1);
  float xn = dpp_add<QPX1>(u0, u1);
  xp = dpp_add<ROR4>(xp, xp);
  xn = dpp_add<ROR4>(xn, xn);
  xp = dpp_add<ROR8>(xp, xp);
  xn = dpp_add<ROR8>(xn, xn);
  // Lane s now holds: xp = projections[head hs+(s&3)], xn = ||m*mem||^2.

  if (sub < 4) {
    const float mnorm = sqrtf(xn);
    const float sharp = xp / fmaf(knorm, mnorm, EPS_) * sp;
    ouths[(size_t)sub * J_ + j] = sharp;
  }
}

// ---------------- Kernel 1: fused coeffs + projection + norm + sharpen --------
// Head-split layout: waves 0-1 compute heads 0-3, waves 2-3 heads 4-7 (sibling
// waves stream the same memory rows; duplicates hit L1/L2, HBM fetch unchanged).
// Within a wave: 4 groups of 16 lanes; each group owns one row per iteration;
// lane sub owns float4 k-chunks {sub, sub+16}.
//
// BAKED-PERMUTATION FOLD REDUCTION: lane s loads head (t ^ (s&3)) into
// coefficient slot t; reduction is quad_perm xor2 -> xor1 -> row_ror:4/8,
// no cndmask selects. Lane ends holding totals for head (lane&3).
//
// THIS REVISION: 2-deep software pipeline. The j-loop is unrolled by 2 with
// four stream buffers — 4 outstanding 16B loads/lane instead of 2 during the
// compute body (latency hiding at 4 waves/SIMD was the R1 bottleneck theory).
// Tail prefetch is CLAMPED to the last row (L1-hot re-read) instead of
// wrapping to row 0 (L2-cold, ~6% extra HBM).
__global__ __launch_bounds__(256, 4) void cw_main(
    const float* __restrict__ memory, const float* __restrict__ keys,
    const float* __restrict__ strengths, const float* __restrict__ mask,
    float* __restrict__ out)
{
  const int bid  = blockIdx.x;
  const int i    = bid >> 6;     // / SBLK
  const int jb   = bid & 63;     // % SBLK
  const int t    = threadIdx.x;
  const int wave = t >> 6;
  const int lane = t & 63;
  const int grp  = lane >> 4;    // 0..3 (row within wave)
  const int sub  = lane & 15;    // 0..15 (k position)
  const int hs   = (wave >> 1) << 2;  // head-set base: 0 or 4
  const int q    = sub & 3;           // this lane's final head (hs + q)

  // ---- Per-block coefficient build (amortized over 128 rows) ----
  const float4* keyv = (const float4*)(keys + (size_t)i * H_ * K_);
  const float4* mskv = (const float4*)(mask + (size_t)i * H_ * K_);
  float4 cA[4][2];   // slot t: mask^2 * keys of head hs + (t^q)
  float4 cB[4][2];   // slot t: mask^2        of head hs + (t^q)
  float knp[4];      // slot t: partial ||mask*keys||^2 of head hs + (t^q)
  #pragma unroll
  for (int tt = 0; tt < 4; ++tt) {
    const int h = hs + (tt ^ q);   // baked fold permutation
    float kp = 0.0f;
    #pragma unroll
    for (int c = 0; c < 2; ++c) {
      const float4 kv = keyv[h * 32 + c * 16 + sub];
      const float4 mv = mskv[h * 32 + c * 16 + sub];
      float4 b, a;
      b.x = mv.x * mv.x; b.y = mv.y * mv.y; b.z = mv.z * mv.z; b.w = mv.w * mv.w;
      a.x = b.x * kv.x;  a.y = b.y * kv.y;  a.z = b.z * kv.z;  a.w = b.w * kv.w;
      cB[tt][c] = b;
      cA[tt][c] = a;
      kp = dot4f(a, kv, kp);   // m^2 * k^2
    }
    knp[tt] = kp;
  }
  // Fold-reduce kn: lane ends with ||mask*keys||^2 of head hs+q.
  {
    const float wk0 = dpp_add<QPX2>(knp[0], knp[2]);
    const float wk1 = dpp_add<QPX2>(knp[1], knp[3]);
    float xk = dpp_add<QPX1>(wk0, wk1);
    xk = dpp_add<ROR4>(xk, xk);
    xk = dpp_add<ROR8>(xk, xk);
    knp[0] = xk;
  }
  const float knorm = sqrtf(knp[0]);
  const float st = strengths[i * H_ + hs + q];
  const float sp = fmaxf(st, 0.0f) + log1pf(expf(-fabsf(st)));  // softplus

  // ---- Stream memory rows (2-deep pipelined) ----
  const int jrow0 = (wave & 1) * 4 + grp;          // row offset within iteration
  const int j0    = jb * JPB + jrow0;
  const float4* rowv = (const float4*)(memory + ((size_t)i * J_ + j0) * K_);
  float* ouths = out + (size_t)(i * H_ + hs) * J_;
  const int jbase = jb * JPB + jrow0;

  // Prologue: rows for it=0 and it=1 in flight.
  float4 a0 = rowv[sub];
  float4 a1 = rowv[sub + 16];
  const float4* r1 = rowv + 256;
  float4 b0 = r1[sub];
  float4 b1 = r1[sub + 16];

  #pragma unroll 1
  for (int it = 0; it < ITERS; it += 2) {
    // Prefetch it+2, it+3 (clamped: tail re-reads the freshest row, L1-hot).
    const int nx2 = (it + 2 < ITERS) ? (it + 2) : (ITERS - 1);
    const int nx3 = (it + 3 < ITERS) ? (it + 3) : (ITERS - 1);
    const float4* nr2 = rowv + (size_t)nx2 * 256;
    const float4* nr3 = rowv + (size_t)nx3 * 256;
    const float4 c0 = nr2[sub];
    const float4 c1 = nr2[sub + 16];
    const float4 d0 = nr3[sub];
    const float4 d1 = nr3[sub + 16];

    cw_row_compute(a0, a1, cA, cB, knorm, sp, sub, jbase + it * RPI, ouths);
    cw_row_compute(b0, b1, cA, cB, knorm, sp, sub, jbase + (it + 1) * RPI, ouths);

    a0 = c0; a1 = c1;
    b0 = d0; b1 = d1;
  }
}

// ---------------- Kernel 2: in-place softmax over J per (i,h) row ----------------
// 1024 threads/block (16 waves); each thread owns 2 float4.
__global__ __launch_bounds__(1024) void cw_softmax(float* __restrict__ out)
{
  const int row = blockIdx.x;   // 0..255
  float4* pv = (float4*)(out + (size_t)row * J_);
  const int t = threadIdx.x;
  const int wave = t >> 6, lane = t & 63;

  float4 v0 = pv[t];
  float4 v1 = pv[t + 1024];
  float mx = fmaxf(fmaxf(fmaxf(v0.x, v0.y), fmaxf(v0.z, v0.w)),
                   fmaxf(fmaxf(v1.x, v1.y), fmaxf(v1.z, v1.w)));
  #pragma unroll
  for (int o = 32; o > 0; o >>= 1) mx = fmaxf(mx, __shfl_xor(mx, o, 64));
  __shared__ float sm[16];
  __shared__ float ss[16];
  if (lane == 0) sm[wave] = mx;
  __syncthreads();
  mx = sm[lane & 15];
  #pragma unroll
  for (int o = 8; o > 0; o >>= 1) mx = fmaxf(mx, __shfl_xor(mx, o, 64));

  v0.x = __expf(v0.x - mx); v0.y = __expf(v0.y - mx);
  v0.z = __expf(v0.z - mx); v0.w = __expf(v0.w - mx);
  v1.x = __expf(v1.x - mx); v1.y = __expf(v1.y - mx);
  v1.z = __expf(v1.z - mx); v1.w = __expf(v1.w - mx);
  float sum = ((v0.x + v0.y) + (v0.z + v0.w)) + ((v1.x + v1.y) + (v1.z + v1.w));
  #pragma unroll
  for (int o = 32; o > 0; o >>= 1) sum += __shfl_xor(sum, o, 64);
  if (lane == 0) ss[wave] = sum;
  __syncthreads();
  sum = ss[lane & 15];
  #pragma unroll
  for (int o = 8; o > 0; o >>= 1) sum += __shfl_xor(sum, o, 64);
  const float inv = 1.0f / sum;

  v0.x *= inv; v0.y *= inv; v0.z *= inv; v0.w *= inv;
  v1.x *= inv; v1.y *= inv; v1.z *= inv; v1.w *= inv;
  pv[t] = v0;
  pv[t + 1024] = v1;
}

extern "C" void kernel_launch(void* const* d_in, const int* in_sizes, int n_in,
                              void* d_out, int out_size, void* d_ws, size_t ws_size,
                              hipStream_t stream) {
  const float* memory    = (const float*)d_in[0];  // [B,J,K]
  const float* keys      = (const float*)d_in[1];  // [B,H,K]
  const float* strengths = (const float*)d_in[2];  // [B,H,1]
  const float* mask      = (const float*)d_in[3];  // [B,H,K]
  float* out = (float*)d_out;                      // [B,H,J]

  // NOTE: d_ws intentionally unused — all coefficients computed in-kernel.
  (void)d_ws; (void)ws_size;

  cw_main<<<B_ * SBLK, 256, 0, stream>>>(memory, keys, strengths, mask, out);
  cw_softmax<<<B_ * H_, 1024, 0, stream>>>(out);
}